// Round 12
// baseline (423.010 us; speedup 1.0000x reference)
//
#include <hip/hip_runtime.h>
#include <stdint.h>

#define BDIM 32
#define CDIM 32
#define LDIM 1024
#define VDIM 4096
#define BCL (BDIM*CDIM*LDIM)

// ---------------------------------------------------------------- init
__global__ void init_kernel(const float* __restrict__ f, const float* __restrict__ emb,
                            float* __restrict__ f_rest, float* __restrict__ f_hat,
                            float* __restrict__ e_sq, float* __restrict__ loss_acc,
                            unsigned* __restrict__ done_ctr,
                            unsigned long long* __restrict__ keys, int nkeys) {
    int i = blockIdx.x * blockDim.x + threadIdx.x;
    if (i < BCL) { f_rest[i] = f[i]; f_hat[i] = 0.0f; }
    if (i < VDIM) {
        const float4* e4 = (const float4*)(emb + (size_t)i * CDIM);
        float s = 0.f;
#pragma unroll
        for (int k = 0; k < 8; ++k) {
            float4 v = e4[k];
            s += v.x*v.x; s += v.y*v.y; s += v.z*v.z; s += v.w*v.w;
        }
        e_sq[i] = s;
    }
    if (i < nkeys) keys[i] = ~0ull;
    if (i == 0) { *loss_acc = 0.f; *done_ctr = 0u; }
}

// ---------------------------------------------------------------- VQ argmin: lane-per-query scan
// ROUND-12: same math as r11 (1 query/lane, 2 codes/iter, broadcast ds_read_b128,
// bit-identical chains + tie-break), but HALF the LDS tile: VC<=128 -> 16.9 KB/block
// -> 8 blocks/CU = 8 waves/SIMD (was 4). Diagnosis r8-r11: scan is LDS-latency exposed
// with no register headroom to prefetch (VGPR 52-64); the cover is TLP, and TLP was
// capped by the 33KB e-tile, not by the allocator (5 failed knob attempts).
__global__ __launch_bounds__(256) void vq_scan(
    const float* __restrict__ f_rest, const float* __restrict__ z_buf,
    const float* __restrict__ emb, const float* __restrict__ e_sq,
    unsigned long long* __restrict__ keys,
    int lpl, int s, int NQ, int VC, int vchunks)
{
    const int pl = 1 << lpl;
    const int t  = threadIdx.x;
    const int qg = blockIdx.x / vchunks;    // 256-query group
    const int vc = blockIdx.x % vchunks;
    const int vb = vc * VC;

    __shared__ __align__(16) float e_ls[128 * 32];   // up to 128 codes x 32 ch (16 KB)
    __shared__ float esq_ls[128];

    // ---- stage code chunk (linear, coalesced; VC*8 float4s over 256 threads)
    {
        const float4* src = (const float4*)emb + (size_t)vb * 8;
        float4* dst = (float4*)e_ls;
        for (int x = t; x < VC * 8; x += 256) dst[x] = src[x];
        if (t < VC) esq_ls[t] = e_sq[vb + t];
    }

    // ---- load this lane's query vector into registers
    const int q  = qg * 256 + t;
    const int qc = (q < NQ) ? q : NQ - 1;

    float z[32];
    if (z_buf) {
        const float4* p = (const float4*)(z_buf + (size_t)qc * 32);
#pragma unroll
        for (int c4 = 0; c4 < 8; ++c4) {
            float4 a = p[c4];
            z[c4*4+0] = a.x; z[c4*4+1] = a.y; z[c4*4+2] = a.z; z[c4*4+3] = a.w;
        }
    } else {
        int b0 = qc >> lpl, j0 = qc & (pl - 1);
        if (pl == LDIM) {
            const float* p = f_rest + b0 * (CDIM * LDIM) + j0;
#pragma unroll
            for (int c = 0; c < 32; ++c) z[c] = p[c * LDIM];
        } else {
            int col = j0 * s + (s >> 1) - 1;
            const float* p = f_rest + b0 * (CDIM * LDIM) + col;
#pragma unroll
            for (int c = 0; c < 32; ++c) z[c] = 0.5f * (p[c * LDIM] + p[c * LDIM + 1]);
        }
    }

    __syncthreads();

    // ---- scan: biased distance d' = e_sq - 2*dot (zz const per query);
    // dual chains over codes v and v+1; chain order c=0..31 (bit-identical).
    float bd = 3.4e38f;
    int bv = 0;

#pragma unroll 1
    for (int v = 0; v < VC; v += 2) {
        const float4* er0 = (const float4*)&e_ls[(size_t)v * 32];
        const float4* er1 = (const float4*)&e_ls[(size_t)(v + 1) * 32];
        float es0 = esq_ls[v];
        float es1 = esq_ls[v + 1];

        float4 p0 = er0[0], p1 = er1[0];
        float a0 = z[0] * p0.x,            a1 = z[0] * p1.x;
        a0 = fmaf(z[1], p0.y, a0);         a1 = fmaf(z[1], p1.y, a1);
        a0 = fmaf(z[2], p0.z, a0);         a1 = fmaf(z[2], p1.z, a1);
        a0 = fmaf(z[3], p0.w, a0);         a1 = fmaf(z[3], p1.w, a1);
#pragma unroll
        for (int c4 = 1; c4 < 8; ++c4) {
            p0 = er0[c4]; p1 = er1[c4];
            a0 = fmaf(z[c4*4+0], p0.x, a0);  a1 = fmaf(z[c4*4+0], p1.x, a1);
            a0 = fmaf(z[c4*4+1], p0.y, a0);  a1 = fmaf(z[c4*4+1], p1.y, a1);
            a0 = fmaf(z[c4*4+2], p0.z, a0);  a1 = fmaf(z[c4*4+2], p1.z, a1);
            a0 = fmaf(z[c4*4+3], p0.w, a0);  a1 = fmaf(z[c4*4+3], p1.w, a1);
        }
        float d0 = fmaf(a0, -2.0f, es0);
        float d1 = fmaf(a1, -2.0f, es1);
        if (d0 < bd) { bd = d0; bv = vb + v; }
        if (d1 < bd) { bd = d1; bv = vb + v + 1; }
    }

    if (q < NQ) {
        unsigned ud = __float_as_uint(bd);
        ud = (ud & 0x80000000u) ? ~ud : (ud | 0x80000000u);
        atomicMin(&keys[q], ((unsigned long long)ud << 32) | (unsigned)bv);
    }
}

// ---------------------------------------------------------------- fused gather+upsample+phi+update+loss
// 64-element L-chunks (grid 16 x 32). Extras: resets next scale's key buffer (ping-pong);
// writes next scale's downsampled queries into z_buf (bit-identical 0.5*(fr[col]+fr[col+1]),
// via LDS since col+1 may belong to a neighboring thread); last scale finalizes the loss.
__global__ __launch_bounds__(256) void fuse_kernel(
    const float* __restrict__ f, const float* __restrict__ emb,
    const unsigned long long* __restrict__ keys,
    unsigned long long* __restrict__ keys_next, int nq_next,
    float* __restrict__ z_next, int s_next,
    const float* __restrict__ w, const float* __restrict__ bias,
    float* __restrict__ f_rest, float* __restrict__ f_hat,
    float* __restrict__ loss_acc, unsigned* __restrict__ done_ctr,
    float* __restrict__ out_loss, int pl)
{
    const int t  = threadIdx.x;
    const int b  = blockIdx.y;
    const int l0 = blockIdx.x * 64;

    // reset next scale's keys (different buffer than 'keys'; safe to do immediately)
    if (keys_next) {
        int x = (b * gridDim.x + blockIdx.x) * 256 + t;   // 512*256 = 131072 >= nq_next
        if (x < nq_next) keys_next[x] = ~0ull;
    }

    __shared__ float w_s[3072];      // [o][i][k]
    __shared__ float b_s[32];
    __shared__ float hs[32 * 68];    // [i][66 (+pad)] : col x -> l = l0 - 1 + x
    __shared__ float red[4];

    for (int x = t; x < 3072; x += 256) w_s[x] = w[x];
    if (t < 32) b_s[t] = bias[t];

    if (t < 66) {
        int l = l0 - 1 + t;
        if (l < 0 || l >= LDIM) {
#pragma unroll
            for (int i = 0; i < 32; ++i) hs[i * 68 + t] = 0.f;
        } else {
            int lo, hi; float wg;
            if (pl == LDIM) { lo = l; hi = l; wg = 0.f; }
            else {
                float pos = (l + 0.5f) * ((float)pl / 1024.0f) - 0.5f;
                pos = fminf(fmaxf(pos, 0.f), (float)(pl - 1));
                lo = (int)floorf(pos);
                hi = min(lo + 1, pl - 1);
                wg = pos - (float)lo;
            }
            int v0 = (int)(keys[b * pl + lo] & 0xFFFFFFFFull);
            int v1 = (int)(keys[b * pl + hi] & 0xFFFFFFFFull);
            const float4* e0 = (const float4*)(emb + (size_t)v0 * 32);
            const float4* e1 = (const float4*)(emb + (size_t)v1 * 32);
            float om = 1.0f - wg;
#pragma unroll
            for (int i4 = 0; i4 < 8; ++i4) {
                float4 a = e0[i4]; float4 c = e1[i4];
                hs[(i4*4+0) * 68 + t] = a.x * om + c.x * wg;
                hs[(i4*4+1) * 68 + t] = a.y * om + c.y * wg;
                hs[(i4*4+2) * 68 + t] = a.z * om + c.z * wg;
                hs[(i4*4+3) * 68 + t] = a.w * om + c.w * wg;
            }
        }
    }
    __syncthreads();

    const int o  = t >> 3;        // output channel, fixed per thread (w reuse x8)
    const int lg = t & 7;         // 8 consecutive l's per thread
    const float* wrow = &w_s[o * 96];
    float acc[8];
#pragma unroll
    for (int u = 0; u < 8; ++u) acc[u] = 0.f;
    const int hbase = lg * 8;     // hs col for l = l0 + lg*8 - 1

    for (int i = 0; i < 32; ++i) {
        float w0 = wrow[i * 3 + 0], w1 = wrow[i * 3 + 1], w2 = wrow[i * 3 + 2];
        const float* hrow = &hs[i * 68 + hbase];
        float hw[10];
#pragma unroll
        for (int x = 0; x < 10; ++x) hw[x] = hrow[x];
#pragma unroll
        for (int u = 0; u < 8; ++u) {
            acc[u] = fmaf(w0, hw[u], acc[u]);
            acc[u] = fmaf(w1, hw[u + 1], acc[u]);
            acc[u] = fmaf(w2, hw[u + 2], acc[u]);
        }
    }

    float lsum = 0.f;
    float frv[8];
    const int gbase = (b * 32 + o) * LDIM + l0 + lg * 8;
#pragma unroll
    for (int u = 0; u < 8; ++u) {
        float hval = hs[o * 68 + lg * 8 + 1 + u];
        float y = acc[u] + b_s[o];
        float ph = 0.5f * hval + 0.5f * y;    // h*(1-RESI) + (conv+b)*RESI, RESI=0.5
        int gi = gbase + u;
        float fh = f_hat[gi] + ph;
        f_hat[gi] = fh;
        float fr = f_rest[gi] - ph;
        f_rest[gi] = fr;
        frv[u] = fr;
        float df = fh - f[gi];
        lsum = fmaf(df, df, lsum);
    }

    // ---- write next scale's downsampled queries (z) from the fresh f_rest values.
    // s_next in {1,4,16,64}; col = j*s + s/2 - 1 stays inside [l0, l0+62] for s<=64.
    if (z_next) {
        __syncthreads();              // all hval reads done
#pragma unroll
        for (int u = 0; u < 8; ++u) hs[o * 68 + lg * 8 + u] = frv[u];   // [c][l-l0]
        __syncthreads();
        int npos = 64 / s_next;
        int qn_base = b * (LDIM / s_next) + l0 / s_next;
        for (int v = t; v < npos * 32; v += 256) {
            int jl = v >> 5, c = v & 31;
            float zv;
            if (s_next == 1) zv = hs[c * 68 + jl];
            else {
                int cl = jl * s_next + (s_next >> 1) - 1;
                zv = 0.5f * (hs[c * 68 + cl] + hs[c * 68 + cl + 1]);
            }
            z_next[(size_t)(qn_base + jl) * 32 + c] = zv;
        }
    }

#pragma unroll
    for (int off = 32; off > 0; off >>= 1) lsum += __shfl_down(lsum, off, 64);
    if ((t & 63) == 0) red[t >> 6] = lsum;
    __syncthreads();
    if (t == 0) {
        atomicAdd(loss_acc, red[0] + red[1] + red[2] + red[3]);
        if (out_loss) {
            __threadfence();
            unsigned old = atomicAdd(done_ctr, 1u);
            if (old == (unsigned)(gridDim.x * gridDim.y - 1)) {
                float lv = atomicAdd(loss_acc, 0.0f);   // coherent read after all adds
                *out_loss = lv * (1.25f / (6.0f * (float)BCL));
            }
        }
    }
}

// ---------------------------------------------------------------- launch
extern "C" void kernel_launch(void* const* d_in, const int* in_sizes, int n_in,
                              void* d_out, int out_size, void* d_ws, size_t ws_size,
                              hipStream_t stream)
{
    const float* f    = (const float*)d_in[0];
    const float* emb  = (const float*)d_in[1];
    const float* phiw = (const float*)d_in[2];
    const float* phib = (const float*)d_in[3];

    float* f_hat    = (float*)d_out;        // BCL floats
    float* out_loss = f_hat + BCL;          // +1 float

    const int pls[6]   = {1, 4, 16, 64, 256, 1024};
    const int lpls[6]  = {0, 2, 4, 6, 8, 10};
    // VC = VDIM/vch <= 128 (16KB e-tile -> 8 blocks/CU).
    // pl=1024: 128 qgroups x 32 = 4096 blocks, VC=128.
    // pl=256: 32 x 64 = 2048 blocks, VC=64. Small scales: VC=64.
    const int vch[6]   = {64, 64, 64, 64, 64, 32};
    const int pidx[6]  = {0, 0, 1, 2, 3, 3};     // PhiPartiallyShared static tick lookup
    const int snx[6]   = {256, 64, 16, 4, 1, 0}; // s of scale si+1 (0 = none)

    char* ws = (char*)d_ws;
    float* f_rest             = (float*)ws;                            // 4 MB
    unsigned long long* keysA = (unsigned long long*)(ws + (size_t)BCL * 4);   // 256 KB

    // Layout: f_rest | keysA | (keysB) | (z_buf 4MB) | e_sq | loss | ctr
    size_t base = (size_t)BCL * 4;
    size_t need_pp   = base + (size_t)65536 * 8 + (size_t)VDIM * 4 + 64;
    size_t need_full = need_pp + (size_t)32768 * 32 * 4;
    bool pp   = ws_size >= need_pp;
    bool zb   = ws_size >= need_full;
    unsigned long long* keysB = pp ? keysA + 32768 : keysA;
    size_t keys_bytes = pp ? (size_t)65536 * 8 : (size_t)32768 * 8;
    float* z_buf = zb ? (float*)(ws + base + keys_bytes) : nullptr;
    size_t zoff  = zb ? (size_t)32768 * 32 * 4 : 0;
    float* e_sq        = (float*)(ws + base + keys_bytes + zoff);
    float* loss_acc    = e_sq + VDIM;
    unsigned* done_ctr = (unsigned*)(loss_acc + 1);

    init_kernel<<<dim3((BCL + 255) / 256), 256, 0, stream>>>(
        f, emb, f_rest, f_hat, e_sq, loss_acc, done_ctr, keysA, 32768);

    for (int si = 0; si < 6; ++si) {
        int pl = pls[si];
        int s  = LDIM / pl;
        int NQ = BDIM * pl;
        int qgroups = (NQ + 255) >> 8;
        int VC = VDIM / vch[si];
        unsigned long long* k  = (si & 1) ? keysB : keysA;
        unsigned long long* kn = (si < 5 && pp) ? ((si & 1) ? keysA : keysB) : nullptr;
        int nq_next = (si < 5) ? BDIM * pls[si + 1] : 0;
        if (!pp && si > 0) hipMemsetAsync(k, 0xFF, (size_t)NQ * 8, stream);
        const float* zread = (zb && si >= 2) ? z_buf : nullptr;
        float* zwrite      = (zb && si >= 1 && si <= 4) ? z_buf : nullptr;
        vq_scan<<<dim3(qgroups * vch[si]), 256, 0, stream>>>(
            f_rest, zread, emb, e_sq, k, lpls[si], s, NQ, VC, vch[si]);
        fuse_kernel<<<dim3(16, 32), 256, 0, stream>>>(
            f, emb, k, kn, nq_next, zwrite, snx[si],
            phiw + (size_t)pidx[si] * 3072, phib + (size_t)pidx[si] * 32,
            f_rest, f_hat, loss_acc, done_ctr,
            (si == 5) ? out_loss : nullptr, pl);
    }
}